// Round 1
// baseline (3340.569 us; speedup 1.0000x reference)
//
#include <hip/hip_runtime.h>

// FavorAttention (Performer FAVOR+) — B=4,H=8,D=64,N=8192,M=256, fp32.
// Round 0: fp32 VALU, scalar-operand FMA structure (no LDS GEMM tiling).
// One GEMM operand per pass is wave-uniform -> s_load + v_fma(scalar,vgpr).

#define Bv 4
#define Hv 8
#define Dv 64
#define Nv 8192
#define Mv 256
#define BHv 32

#define DNRM 0.3535533905932738f   // 64^-0.25
#define RATIO 0.0625f              // 256^-0.5
#define EPSV 1e-6f

// workspace layout (floats)
#define OFF_DIAGK 0                          // [BH][N] diag_k
#define OFF_PARTIAL (BHv * Nv)               // [BH][32] per-block max partials
#define OFF_STAB (OFF_PARTIAL + BHv * 32)    // [BH] global k stabilizer
#define OFF_KN (OFF_STAB + BHv)              // [BH][M] key_norm (atomic)
#define OFF_KV (OFF_KN + BHv * Mv)           // [BH][M][D] kv (atomic)
#define WS_FLOATS (OFF_KV + BHv * Mv * Dv)   // ~795680 floats = 3.04 MB

// ---------------------------------------------------------------------------
// K_A: per column n of K: diag_k[n] = ||K[:,n]||^2 * dn^2/2, and block-max of
// raw u[m,n] = sum_d P[m,d]*K[d,n] over all m and the block's 256 columns.
__global__ __launch_bounds__(256) void favor_kmax(const float* __restrict__ key,
                                                  const float* __restrict__ proj,
                                                  float* __restrict__ ws) {
    const int tid = threadIdx.x;
    const int chunk = blockIdx.x;  // 0..31
    const int bh = blockIdx.y;     // 0..31
    const int n = chunk * 256 + tid;
    const float* kp = key + (size_t)bh * Dv * Nv;

    float kc[Dv];
    float ss = 0.f;
#pragma unroll
    for (int d = 0; d < Dv; ++d) {
        kc[d] = kp[d * Nv + n];   // coalesced: lanes -> consecutive n
        ss += kc[d] * kc[d];
    }
    ws[OFF_DIAGK + bh * Nv + n] = ss * 0.0625f;  // dn^2 * 0.5 = 0.0625

    float cmax = -3.4e38f;
    for (int m = 0; m < Mv; ++m) {
        const float* pr = proj + m * Dv;  // wave-uniform -> scalar loads
        float u = 0.f;
#pragma unroll
        for (int d = 0; d < Dv; ++d) u += pr[d] * kc[d];
        cmax = fmaxf(cmax, u);
    }
    // wave64 shuffle-max, then cross-wave via LDS
    for (int off = 32; off; off >>= 1) cmax = fmaxf(cmax, __shfl_down(cmax, off));
    __shared__ float red[4];
    if ((tid & 63) == 0) red[tid >> 6] = cmax;
    __syncthreads();
    if (tid == 0) {
        float r = fmaxf(fmaxf(red[0], red[1]), fmaxf(red[2], red[3]));
        ws[OFF_PARTIAL + bh * 32 + chunk] = r;  // raw (unscaled) max
    }
}

// ---------------------------------------------------------------------------
// K_A2: stab_k[bh] = dn * max over the 32 block partials.
__global__ void favor_stab(float* __restrict__ ws) {
    int bh = threadIdx.x;
    if (bh < BHv) {
        float r = -3.4e38f;
        for (int j = 0; j < 32; ++j) r = fmaxf(r, ws[OFF_PARTIAL + bh * 32 + j]);
        ws[OFF_STAB + bh] = r * DNRM;
    }
}

// ---------------------------------------------------------------------------
// K_B: thread m owns kv row m. K/V columns are wave-uniform (scalar dwordx8
// batches of 8 columns). kv[m][d] += phi_k[m,n]*V[d,n]; key_norm[m] += phi_k.
__global__ __launch_bounds__(256) void favor_kv(const float* __restrict__ key,
                                                const float* __restrict__ value,
                                                const float* __restrict__ proj,
                                                float* __restrict__ ws) {
    const int m = threadIdx.x;     // 0..255
    const int chunk = blockIdx.x;  // 32 chunks x 256 columns
    const int bh = blockIdx.y;
    const int n0 = chunk * 256;
    const float* kp = key + (size_t)bh * Dv * Nv;
    const float* vp = value + (size_t)bh * Dv * Nv;
    const float stab = ws[OFF_STAB + bh];
    const float* diagp = ws + OFF_DIAGK + bh * Nv;

    float p[Dv];
#pragma unroll
    for (int d = 0; d < Dv; ++d) p[d] = proj[m * Dv + d];

    float kv[Dv];
#pragma unroll
    for (int d = 0; d < Dv; ++d) kv[d] = 0.f;
    float kn = 0.f;

    for (int nb = 0; nb < 256; nb += 8) {
        float u[8];
#pragma unroll
        for (int j = 0; j < 8; ++j) u[j] = 0.f;
#pragma unroll
        for (int d = 0; d < Dv; ++d) {
            const float* kr = kp + d * Nv + n0 + nb;  // wave-uniform, 8 consecutive
#pragma unroll
            for (int j = 0; j < 8; ++j) u[j] += p[d] * kr[j];
        }
        float phi[8];
#pragma unroll
        for (int j = 0; j < 8; ++j) {
            float e = __expf(u[j] * DNRM - diagp[n0 + nb + j] - stab);
            phi[j] = RATIO * (e + EPSV);
            kn += phi[j];
        }
#pragma unroll
        for (int d = 0; d < Dv; ++d) {
            const float* vr = vp + d * Nv + n0 + nb;  // wave-uniform
            float acc = kv[d];
#pragma unroll
            for (int j = 0; j < 8; ++j) acc += phi[j] * vr[j];
            kv[d] = acc;
        }
    }
    float* kvp = ws + OFF_KV + ((size_t)bh * Mv + m) * Dv;
#pragma unroll
    for (int d = 0; d < Dv; ++d) atomicAdd(&kvp[d], kv[d]);
    atomicAdd(&ws[OFF_KN + bh * Mv + m], kn);
}

// ---------------------------------------------------------------------------
// K_C: thread-per-column n of Q. Pass A: per-token max over m. Pass B:
// recompute u, e = exp(u-diag-stab)+eps; out[d] = sum_m e*kv[m][d];
// norm = sum_m e*key_norm[m]. The ratio factors cancel in out/norm exactly.
// kv/key_norm reads are wave-uniform scalar loads (written by prior kernel).
__global__ __launch_bounds__(256) void favor_out(const float* __restrict__ query,
                                                 const float* __restrict__ proj,
                                                 const float* __restrict__ ws,
                                                 float* __restrict__ out) {
    const int tid = threadIdx.x;
    const int chunk = blockIdx.x;
    const int bh = blockIdx.y;
    const int n = chunk * 256 + tid;
    const float* qp = query + (size_t)bh * Dv * Nv;

    float qc[Dv];
    float ss = 0.f;
#pragma unroll
    for (int d = 0; d < Dv; ++d) {
        qc[d] = qp[d * Nv + n];  // coalesced
        ss += qc[d] * qc[d];
    }
    const float diag = ss * 0.0625f;

    // pass A: per-column max over m (exact stabilizer, matches reference)
    float cmax = -3.4e38f;
    for (int m = 0; m < Mv; ++m) {
        const float* pr = proj + m * Dv;
        float u = 0.f;
#pragma unroll
        for (int d = 0; d < Dv; ++d) u += pr[d] * qc[d];
        cmax = fmaxf(cmax, u);
    }
    const float stab = cmax * DNRM;

    // pass B: recompute u, accumulate output
    const float* kvp = ws + OFF_KV + (size_t)bh * Mv * Dv;
    const float* knp = ws + OFF_KN + bh * Mv;
    float acc[Dv];
#pragma unroll
    for (int d = 0; d < Dv; ++d) acc[d] = 0.f;
    float nrm = 0.f;
    for (int m = 0; m < Mv; ++m) {
        const float* pr = proj + m * Dv;
        float u = 0.f;
#pragma unroll
        for (int d = 0; d < Dv; ++d) u += pr[d] * qc[d];
        float e = __expf(u * DNRM - diag - stab) + EPSV;
        nrm += e * knp[m];
        const float* kvr = kvp + m * Dv;  // wave-uniform row
#pragma unroll
        for (int d = 0; d < Dv; ++d) acc[d] += e * kvr[d];
    }
    const float rn = 1.f / nrm;
    float* op = out + (size_t)bh * Dv * Nv;
#pragma unroll
    for (int d = 0; d < Dv; ++d) op[d * Nv + n] = acc[d] * rn;  // coalesced, [D,N]
}

// ---------------------------------------------------------------------------
extern "C" void kernel_launch(void* const* d_in, const int* in_sizes, int n_in,
                              void* d_out, int out_size, void* d_ws, size_t ws_size,
                              hipStream_t stream) {
    const float* q = (const float*)d_in[0];
    const float* k = (const float*)d_in[1];
    const float* v = (const float*)d_in[2];
    const float* proj = (const float*)d_in[3];
    float* ws = (float*)d_ws;
    float* out = (float*)d_out;

    // zero the atomic-accumulated regions (kn + kv are adjacent)
    hipMemsetAsync(ws + OFF_KN, 0, (size_t)(BHv * Mv + BHv * Mv * Dv) * sizeof(float),
                   stream);

    favor_kmax<<<dim3(32, 32), 256, 0, stream>>>(k, proj, ws);
    favor_stab<<<1, 64, 0, stream>>>(ws);
    favor_kv<<<dim3(32, 32), 256, 0, stream>>>(k, v, proj, ws);
    favor_out<<<dim3(32, 32), 256, 0, stream>>>(q, proj, ws, out);
}

// Round 2
// 399.594 us; speedup vs baseline: 8.3599x; 8.3599x over previous
//
#include <hip/hip_runtime.h>

// FavorAttention (Performer FAVOR+) — B=4,H=8,D=64,N=8192,M=256, fp32 in/out.
// R1: bf16 MFMA 16x16x32 pipeline. ratio cancels in num/denom (kept eps).
// Layouts (HW-verified per guide): A[m=lane&15][k=(lane>>4)*8+j],
// B[k=(lane>>4)*8+j][n=lane&15], D: col=lane&15, row=(lane>>4)*4+reg.

typedef short s16x8 __attribute__((ext_vector_type(8)));
typedef float f32x4 __attribute__((ext_vector_type(4)));

#define Dv 64
#define Nv 8192
#define Mv 256
#define BHv 32
#define SPL 16
#define NSPL (Nv / SPL)   // 512
#define NCH (NSPL / 64)   // 8 chunks of 64 columns

#define DNRM 0.3535533905932738f   // 64^-0.25
#define EPSV 1e-6f

// ws layout (float offsets)
#define OFF_DIAGK 0
#define OFF_DIAGQ (BHv * Nv)                    // 262144
#define OFF_MAXP (2 * BHv * Nv)                 // [32][16]
#define OFF_STAB (OFF_MAXP + BHv * SPL)
#define OFF_KNP (OFF_STAB + BHv)                // [32][16][256]
#define OFF_KNF (OFF_KNP + BHv * SPL * Mv)      // [32][256]
#define OFF_KVP (OFF_KNF + BHv * Mv)            // [32][16][256][64] fp32
#define OFF_KVT (OFF_KVP + BHv * SPL * Mv * Dv) // [32][64][256] bf16 (ushort)

__device__ __forceinline__ unsigned short f2b(float x) {
    return __builtin_bit_cast(unsigned short, (__bf16)x);
}
__device__ __forceinline__ float b2f(unsigned short u) {
    unsigned int t = ((unsigned int)u) << 16;
    return __builtin_bit_cast(float, t);
}

// P fragment for (m, kc): 8 consecutive d at kc*32 + q*8 — works as A-frag
// (row m=lane&15) or B-frag (col m=lane&15) since P is the [m][d] operand.
__device__ __forceinline__ s16x8 load_pfrag(const float* __restrict__ proj, int m,
                                            int kc, int q) {
    const float* p = proj + m * 64 + kc * 32 + q * 8;
    s16x8 r;
#pragma unroll
    for (int j = 0; j < 8; ++j) r[j] = (short)f2b(p[j]);
    return r;
}

// ---------------------------------------------------------------------------
// diag: per-column ||x||^2 * 0.0625 for K (z=0) and Q (z=1).
__global__ __launch_bounds__(256) void favor_diag(const float* __restrict__ key,
                                                  const float* __restrict__ query,
                                                  float* __restrict__ ws) {
    const int t = threadIdx.x, xb = blockIdx.x, bh = blockIdx.y, z = blockIdx.z;
    const float* xp = (z ? query : key) + (size_t)bh * Dv * Nv;
    float* dst = ws + (z ? OFF_DIAGQ : OFF_DIAGK) + bh * Nv;
    const int n = xb * 1024 + t * 4;
    float s0 = 0.f, s1 = 0.f, s2 = 0.f, s3 = 0.f;
    for (int d = 0; d < 64; ++d) {
        const float4 v = *(const float4*)&xp[d * Nv + n];
        s0 += v.x * v.x; s1 += v.y * v.y; s2 += v.z * v.z; s3 += v.w * v.w;
    }
    *(float4*)&dst[n] = make_float4(s0 * 0.0625f, s1 * 0.0625f, s2 * 0.0625f,
                                    s3 * 0.0625f);
}

// ---------------------------------------------------------------------------
// kmax: global max of raw u = P·K (bf16 mfma, same products as favor_kv).
__global__ __launch_bounds__(256, 3) void favor_kmax(const float* __restrict__ key,
                                                     const float* __restrict__ proj,
                                                     float* __restrict__ ws) {
    __shared__ __align__(16) unsigned short KT[64][72];  // [n][d] bf16
    __shared__ float red[4];
    const int tid = threadIdx.x;
    const int w = tid >> 6, l = tid & 63, c = l & 15, q = l >> 4;
    const int s = blockIdx.x, bh = blockIdx.y;
    const float* kp = key + (size_t)bh * Dv * Nv;

    s16x8 P[4][2];
#pragma unroll
    for (int mt = 0; mt < 4; ++mt)
#pragma unroll
        for (int kc = 0; kc < 2; ++kc)
            P[mt][kc] = load_pfrag(proj, (4 * w + mt) * 16 + c, kc, q);

    float vmax = -3.4e38f;
    for (int ch = 0; ch < NCH; ++ch) {
        const int n0 = s * NSPL + ch * 64;
        if (ch) __syncthreads();
#pragma unroll
        for (int i = 0; i < 4; ++i) {
            const int d = i * 16 + (tid >> 4), n4 = (tid & 15) * 4;
            const float4 kk = *(const float4*)&kp[d * Nv + n0 + n4];
            KT[n4 + 0][d] = f2b(kk.x); KT[n4 + 1][d] = f2b(kk.y);
            KT[n4 + 2][d] = f2b(kk.z); KT[n4 + 3][d] = f2b(kk.w);
        }
        __syncthreads();
#pragma unroll
        for (int nt = 0; nt < 4; ++nt) {
            const s16x8 a0 = *(const s16x8*)&KT[nt * 16 + c][q * 8];
            const s16x8 a1 = *(const s16x8*)&KT[nt * 16 + c][32 + q * 8];
#pragma unroll
            for (int mt = 0; mt < 4; ++mt) {
                f32x4 u = {0.f, 0.f, 0.f, 0.f};
                u = __builtin_amdgcn_mfma_f32_16x16x32_bf16(a0, P[mt][0], u, 0, 0, 0);
                u = __builtin_amdgcn_mfma_f32_16x16x32_bf16(a1, P[mt][1], u, 0, 0, 0);
                vmax = fmaxf(vmax, fmaxf(fmaxf(u[0], u[1]), fmaxf(u[2], u[3])));
            }
        }
    }
#pragma unroll
    for (int off = 1; off < 64; off <<= 1)
        vmax = fmaxf(vmax, __shfl_xor(vmax, off, 64));
    if (l == 0) red[w] = vmax;
    __syncthreads();
    if (tid == 0)
        ws[OFF_MAXP + bh * SPL + s] =
            fmaxf(fmaxf(red[0], red[1]), fmaxf(red[2], red[3]));
}

__global__ void favor_stab(float* __restrict__ ws) {
    const int t = threadIdx.x;
    if (t < BHv) {
        float r = -3.4e38f;
        for (int s = 0; s < SPL; ++s) r = fmaxf(r, ws[OFF_MAXP + t * SPL + s]);
        ws[OFF_STAB + t] = r * DNRM;
    }
}

// ---------------------------------------------------------------------------
// kv: fused  U^T = K^T·P^T  → exp → phi (LDS roundtrip) →  kv += phi·V^T.
__global__ __launch_bounds__(256, 2) void favor_kv(const float* __restrict__ key,
                                                   const float* __restrict__ value,
                                                   const float* __restrict__ proj,
                                                   float* __restrict__ ws) {
    __shared__ __align__(16) unsigned short KT[64][72];   // [n][d]
    __shared__ __align__(16) unsigned short VL[64][72];   // [d][n]
    __shared__ __align__(16) unsigned short PH[256][72];  // [m][n] phi bf16
    const int tid = threadIdx.x;
    const int w = tid >> 6, l = tid & 63, c = l & 15, q = l >> 4;
    const int s = blockIdx.x, bh = blockIdx.y;
    const float* kp = key + (size_t)bh * Dv * Nv;
    const float* vp = value + (size_t)bh * Dv * Nv;
    const float stab = ws[OFF_STAB + bh];
    const float* dgp = ws + OFF_DIAGK + bh * Nv;

    s16x8 P[4][2];
#pragma unroll
    for (int mt = 0; mt < 4; ++mt)
#pragma unroll
        for (int kc = 0; kc < 2; ++kc)
            P[mt][kc] = load_pfrag(proj, (4 * w + mt) * 16 + c, kc, q);

    f32x4 kva[4][4];
#pragma unroll
    for (int mt = 0; mt < 4; ++mt)
#pragma unroll
        for (int dt = 0; dt < 4; ++dt) kva[mt][dt] = (f32x4){0.f, 0.f, 0.f, 0.f};
    float kn[4] = {0.f, 0.f, 0.f, 0.f};

    for (int ch = 0; ch < NCH; ++ch) {
        const int n0 = s * NSPL + ch * 64;
        if (ch) __syncthreads();
#pragma unroll
        for (int i = 0; i < 4; ++i) {
            const int d = i * 16 + (tid >> 4), n4 = (tid & 15) * 4;
            const float4 kk = *(const float4*)&kp[d * Nv + n0 + n4];
            KT[n4 + 0][d] = f2b(kk.x); KT[n4 + 1][d] = f2b(kk.y);
            KT[n4 + 2][d] = f2b(kk.z); KT[n4 + 3][d] = f2b(kk.w);
            const float4 vv = *(const float4*)&vp[d * Nv + n0 + n4];
            VL[d][n4 + 0] = f2b(vv.x); VL[d][n4 + 1] = f2b(vv.y);
            VL[d][n4 + 2] = f2b(vv.z); VL[d][n4 + 3] = f2b(vv.w);
        }
        __syncthreads();
        // GEMM1: D[n][m] = sum_d KT[n][d] * P[m][d]  (wave-local rows m)
#pragma unroll
        for (int nt = 0; nt < 4; ++nt) {
            const s16x8 a0 = *(const s16x8*)&KT[nt * 16 + c][q * 8];
            const s16x8 a1 = *(const s16x8*)&KT[nt * 16 + c][32 + q * 8];
            const float4 dg = *(const float4*)&dgp[n0 + nt * 16 + q * 4];
#pragma unroll
            for (int mt = 0; mt < 4; ++mt) {
                f32x4 u = {0.f, 0.f, 0.f, 0.f};
                u = __builtin_amdgcn_mfma_f32_16x16x32_bf16(a0, P[mt][0], u, 0, 0, 0);
                u = __builtin_amdgcn_mfma_f32_16x16x32_bf16(a1, P[mt][1], u, 0, 0, 0);
                const float e0 = __expf(u[0] * DNRM - dg.x - stab) + EPSV;
                const float e1 = __expf(u[1] * DNRM - dg.y - stab) + EPSV;
                const float e2 = __expf(u[2] * DNRM - dg.z - stab) + EPSV;
                const float e3 = __expf(u[3] * DNRM - dg.w - stab) + EPSV;
                kn[mt] += (e0 + e1) + (e2 + e3);
                const int m = (4 * w + mt) * 16 + c;
                *(short2*)&PH[m][nt * 16 + q * 4] =
                    make_short2((short)f2b(e0), (short)f2b(e1));
                *(short2*)&PH[m][nt * 16 + q * 4 + 2] =
                    make_short2((short)f2b(e2), (short)f2b(e3));
            }
        }
        // GEMM2: kv[m][d] += phi[m][n] * V^T[n][d]
#pragma unroll
        for (int kc = 0; kc < 2; ++kc) {
            s16x8 bf[4];
#pragma unroll
            for (int dt = 0; dt < 4; ++dt)
                bf[dt] = *(const s16x8*)&VL[dt * 16 + c][kc * 32 + q * 8];
#pragma unroll
            for (int mt = 0; mt < 4; ++mt) {
                const s16x8 a =
                    *(const s16x8*)&PH[(4 * w + mt) * 16 + c][kc * 32 + q * 8];
#pragma unroll
                for (int dt = 0; dt < 4; ++dt)
                    kva[mt][dt] = __builtin_amdgcn_mfma_f32_16x16x32_bf16(
                        a, bf[dt], kva[mt][dt], 0, 0, 0);
            }
        }
    }
    // store split partials (no atomics)
    float* kvp = ws + OFF_KVP + (size_t)(bh * SPL + s) * Mv * Dv;
#pragma unroll
    for (int mt = 0; mt < 4; ++mt) {
        const int mrow = (4 * w + mt) * 16 + 4 * q;
#pragma unroll
        for (int dt = 0; dt < 4; ++dt) {
            const int dcol = dt * 16 + c;
#pragma unroll
            for (int r = 0; r < 4; ++r)
                kvp[(size_t)(mrow + r) * Dv + dcol] = kva[mt][dt][r];
        }
    }
#pragma unroll
    for (int mt = 0; mt < 4; ++mt) {
        kn[mt] += __shfl_xor(kn[mt], 16, 64);
        kn[mt] += __shfl_xor(kn[mt], 32, 64);
    }
    if (q == 0) {
        float* knp = ws + OFF_KNP + (bh * SPL + s) * Mv;
#pragma unroll
        for (int mt = 0; mt < 4; ++mt) knp[(4 * w + mt) * 16 + c] = kn[mt];
    }
}

// ---------------------------------------------------------------------------
// reduce splits → kvT bf16 [bh][d][m] + kn_final fp32
__global__ __launch_bounds__(256) void favor_kvred(float* __restrict__ ws) {
    const int t = threadIdx.x, bh = blockIdx.x;
    float acc[64];
#pragma unroll
    for (int d = 0; d < 64; ++d) acc[d] = 0.f;
    for (int s = 0; s < SPL; ++s) {
        const float* row = ws + OFF_KVP + ((size_t)(bh * SPL + s) * Mv + t) * Dv;
#pragma unroll
        for (int dq = 0; dq < 16; ++dq) {
            const float4 v = *(const float4*)&row[dq * 4];
            acc[dq * 4] += v.x; acc[dq * 4 + 1] += v.y;
            acc[dq * 4 + 2] += v.z; acc[dq * 4 + 3] += v.w;
        }
    }
    unsigned short* kvT = (unsigned short*)(ws + OFF_KVT);
#pragma unroll
    for (int d = 0; d < 64; ++d) kvT[(bh * 64 + d) * 256 + t] = f2b(acc[d]);
    float kn = 0.f;
    for (int s = 0; s < SPL; ++s) kn += ws[OFF_KNP + (bh * SPL + s) * Mv + t];
    ws[OFF_KNF + bh * Mv + t] = kn;
}

// ---------------------------------------------------------------------------
// out: U = P·Q → per-column max → phi_q → out = phi_q^T·kv, norm, store [D][N].
__global__ __launch_bounds__(256, 3) void favor_out(const float* __restrict__ query,
                                                    const float* __restrict__ proj,
                                                    const float* __restrict__ ws,
                                                    float* __restrict__ out) {
    __shared__ __align__(16) unsigned short QT[64][72];    // [n][d]
    __shared__ __align__(16) unsigned short PHT[64][264];  // [n][m] phi^T bf16
    __shared__ float npart[4][64];
    __shared__ float norm_lds[64];
    __shared__ float knl[256];
    __shared__ float cw[4][64];
    __shared__ float stabl[64];
    const int tid = threadIdx.x;
    const int w = tid >> 6, l = tid & 63, c = l & 15, q = l >> 4;
    const int nb = blockIdx.x, bh = blockIdx.y;
    const int n0 = nb * 64;
    const float* qp = query + (size_t)bh * Dv * Nv;
    const float* dgp = ws + OFF_DIAGQ + bh * Nv;
    const unsigned short* kvT =
        (const unsigned short*)(ws + OFF_KVT) + (size_t)bh * 64 * 256;

#pragma unroll
    for (int i = 0; i < 4; ++i) {
        const int d = i * 16 + (tid >> 4), n4 = (tid & 15) * 4;
        const float4 qq = *(const float4*)&qp[d * Nv + n0 + n4];
        QT[n4 + 0][d] = f2b(qq.x); QT[n4 + 1][d] = f2b(qq.y);
        QT[n4 + 2][d] = f2b(qq.z); QT[n4 + 3][d] = f2b(qq.w);
    }
    knl[tid] = ws[OFF_KNF + bh * Mv + tid];

    s16x8 P[4][2];
#pragma unroll
    for (int mt = 0; mt < 4; ++mt)
#pragma unroll
        for (int kc = 0; kc < 2; ++kc)
            P[mt][kc] = load_pfrag(proj, (4 * w + mt) * 16 + c, kc, q);
    __syncthreads();

    // GEMM_uq: D[m][n], wave w owns m = 64w..64w+63, all 64 n
    f32x4 u[4][4];
#pragma unroll
    for (int mt = 0; mt < 4; ++mt)
#pragma unroll
        for (int nt = 0; nt < 4; ++nt) u[mt][nt] = (f32x4){0.f, 0.f, 0.f, 0.f};
#pragma unroll
    for (int nt = 0; nt < 4; ++nt) {
        const s16x8 b0 = *(const s16x8*)&QT[nt * 16 + c][q * 8];
        const s16x8 b1 = *(const s16x8*)&QT[nt * 16 + c][32 + q * 8];
#pragma unroll
        for (int mt = 0; mt < 4; ++mt) {
            u[mt][nt] =
                __builtin_amdgcn_mfma_f32_16x16x32_bf16(P[mt][0], b0, u[mt][nt], 0, 0, 0);
            u[mt][nt] =
                __builtin_amdgcn_mfma_f32_16x16x32_bf16(P[mt][1], b1, u[mt][nt], 0, 0, 0);
        }
    }
    // per-column max over m
#pragma unroll
    for (int nt = 0; nt < 4; ++nt) {
        float vm = -3.4e38f;
#pragma unroll
        for (int mt = 0; mt < 4; ++mt)
            vm = fmaxf(vm, fmaxf(fmaxf(u[mt][nt][0], u[mt][nt][1]),
                                 fmaxf(u[mt][nt][2], u[mt][nt][3])));
        vm = fmaxf(vm, __shfl_xor(vm, 16, 64));
        vm = fmaxf(vm, __shfl_xor(vm, 32, 64));
        if (q == 0) cw[w][nt * 16 + c] = vm;
    }
    __syncthreads();
    if (tid < 64)
        stabl[tid] = fmaxf(fmaxf(cw[0][tid], cw[1][tid]), fmaxf(cw[2][tid], cw[3][tid]));
    __syncthreads();
    // exp → phi^T  (exp((u - rawmax)*dn - diag) == exp(u*dn - diag - stab))
#pragma unroll
    for (int nt = 0; nt < 4; ++nt) {
        const float sr = stabl[nt * 16 + c];
        const float dq = dgp[n0 + nt * 16 + c];
#pragma unroll
        for (int mt = 0; mt < 4; ++mt) {
            const float e0 = __expf((u[mt][nt][0] - sr) * DNRM - dq) + EPSV;
            const float e1 = __expf((u[mt][nt][1] - sr) * DNRM - dq) + EPSV;
            const float e2 = __expf((u[mt][nt][2] - sr) * DNRM - dq) + EPSV;
            const float e3 = __expf((u[mt][nt][3] - sr) * DNRM - dq) + EPSV;
            const int mcol = (4 * w + mt) * 16 + q * 4;
            *(short2*)&PHT[nt * 16 + c][mcol] =
                make_short2((short)f2b(e0), (short)f2b(e1));
            *(short2*)&PHT[nt * 16 + c][mcol + 2] =
                make_short2((short)f2b(e2), (short)f2b(e3));
        }
    }
    __syncthreads();
    // denominator: norm[n] = sum_m phi^T[n][m] * kn[m]
    {
        const int n = tid & 63, mq = tid >> 6;
        float a = 0.f;
#pragma unroll
        for (int mi = 0; mi < 32; ++mi) {
            const int m = mq * 64 + mi * 2;
            const short2 pp = *(const short2*)&PHT[n][m];
            a += b2f((unsigned short)pp.x) * knl[m] +
                 b2f((unsigned short)pp.y) * knl[m + 1];
        }
        npart[mq][n] = a;
    }
    __syncthreads();
    if (tid < 64)
        norm_lds[tid] = (npart[0][tid] + npart[1][tid]) + (npart[2][tid] + npart[3][tid]);
    __syncthreads();
    // out GEMM: wave w owns n-tile w; kv^T B-frags direct from global (L2-hot)
    f32x4 acc[4];
#pragma unroll
    for (int dt = 0; dt < 4; ++dt) acc[dt] = (f32x4){0.f, 0.f, 0.f, 0.f};
#pragma unroll
    for (int kc = 0; kc < 8; ++kc) {
        const s16x8 a = *(const s16x8*)&PHT[w * 16 + c][kc * 32 + q * 8];
#pragma unroll
        for (int dt = 0; dt < 4; ++dt) {
            const s16x8 b =
                *(const s16x8*)&kvT[(size_t)(dt * 16 + c) * 256 + kc * 32 + q * 8];
            acc[dt] = __builtin_amdgcn_mfma_f32_16x16x32_bf16(a, b, acc[dt], 0, 0, 0);
        }
    }
    __syncthreads();  // all waves done reading PHT; reuse as fp32 out tile
    float* ot = (float*)&PHT[0][0];  // [64 d][68 n]
    float rn[4];
#pragma unroll
    for (int r = 0; r < 4; ++r) rn[r] = 1.0f / norm_lds[w * 16 + q * 4 + r];
#pragma unroll
    for (int dt = 0; dt < 4; ++dt)
#pragma unroll
        for (int r = 0; r < 4; ++r)
            ot[(dt * 16 + c) * 68 + (w * 16 + q * 4 + r)] = acc[dt][r] * rn[r];
    __syncthreads();
    float* op = out + (size_t)bh * Dv * Nv;
    {
        const int d = tid >> 2, ng = (tid & 3) * 16;
#pragma unroll
        for (int i = 0; i < 4; ++i) {
            const float4 v = *(const float4*)&ot[d * 68 + ng + i * 4];
            *(float4*)&op[d * Nv + n0 + ng + i * 4] = v;
        }
    }
}

// ---------------------------------------------------------------------------
extern "C" void kernel_launch(void* const* d_in, const int* in_sizes, int n_in,
                              void* d_out, int out_size, void* d_ws, size_t ws_size,
                              hipStream_t stream) {
    const float* q = (const float*)d_in[0];
    const float* k = (const float*)d_in[1];
    const float* v = (const float*)d_in[2];
    const float* proj = (const float*)d_in[3];
    float* ws = (float*)d_ws;
    float* out = (float*)d_out;

    favor_diag<<<dim3(8, 32, 2), 256, 0, stream>>>(k, q, ws);
    favor_kmax<<<dim3(SPL, 32), 256, 0, stream>>>(k, proj, ws);
    favor_stab<<<1, 64, 0, stream>>>(ws);
    favor_kv<<<dim3(SPL, 32), 256, 0, stream>>>(k, v, proj, ws);
    favor_kvred<<<32, 256, 0, stream>>>(ws);
    favor_out<<<dim3(Nv / 64, 32), 256, 0, stream>>>(q, proj, ws, out);
}

// Round 3
// 352.259 us; speedup vs baseline: 9.4833x; 1.1344x over previous
//
#include <hip/hip_runtime.h>

// FavorAttention (Performer FAVOR+) — B=4,H=8,D=64,N=8192,M=256, fp32 in/out.
// R2: bf16 MFMA pipeline; in-register denominator (kills 8-way LDS conflict
// loop), b64 staging writes, diag_q fused into favor_out, coalesced kvred.

typedef short s16x8 __attribute__((ext_vector_type(8)));
typedef float f32x4 __attribute__((ext_vector_type(4)));

#define Dv 64
#define Nv 8192
#define Mv 256
#define BHv 32
#define SPL 16
#define NSPL (Nv / SPL)   // 512
#define NCH (NSPL / 64)   // 8

#define DNRM 0.3535533905932738f   // 64^-0.25
#define EPSV 1e-6f

// ws layout (float offsets)
#define OFF_DIAGK 0
#define OFF_MAXP (BHv * Nv)
#define OFF_STAB (OFF_MAXP + BHv * SPL)
#define OFF_KNP (OFF_STAB + BHv)                 // [32][16][256]
#define OFF_KNF (OFF_KNP + BHv * SPL * Mv)       // [32][256]
#define OFF_KVP (OFF_KNF + BHv * Mv)             // [32][16][256][64] fp32
#define OFF_KVT (OFF_KVP + BHv * SPL * Mv * Dv)  // [32][64][256] bf16

__device__ __forceinline__ unsigned short f2b(float x) {
    return __builtin_bit_cast(unsigned short, (__bf16)x);
}

__device__ __forceinline__ s16x8 load_pfrag(const float* __restrict__ proj, int m,
                                            int kc, int q) {
    const float* p = proj + m * 64 + kc * 32 + q * 8;
    s16x8 r;
#pragma unroll
    for (int j = 0; j < 8; ++j) r[j] = (short)f2b(p[j]);
    return r;
}

// ---------------------------------------------------------------------------
// diag_k only (diag_q is fused into favor_out). Near-HBM-roofline already.
__global__ __launch_bounds__(256) void favor_diag(const float* __restrict__ key,
                                                  float* __restrict__ ws) {
    const int t = threadIdx.x, xb = blockIdx.x, bh = blockIdx.y;
    const float* xp = key + (size_t)bh * Dv * Nv;
    float* dst = ws + OFF_DIAGK + bh * Nv;
    const int n = xb * 1024 + t * 4;
    float s0 = 0.f, s1 = 0.f, s2 = 0.f, s3 = 0.f;
    for (int d = 0; d < 64; ++d) {
        const float4 v = *(const float4*)&xp[d * Nv + n];
        s0 += v.x * v.x; s1 += v.y * v.y; s2 += v.z * v.z; s3 += v.w * v.w;
    }
    *(float4*)&dst[n] = make_float4(s0 * 0.0625f, s1 * 0.0625f, s2 * 0.0625f,
                                    s3 * 0.0625f);
}

// ---------------------------------------------------------------------------
// kmax: global max of raw u = P·K (same bf16 products as favor_kv).
__global__ __launch_bounds__(256, 2) void favor_kmax(const float* __restrict__ key,
                                                     const float* __restrict__ proj,
                                                     float* __restrict__ ws) {
    __shared__ __align__(16) unsigned short KT[64][72];  // [n][d] bf16
    __shared__ float red[4];
    const int tid = threadIdx.x;
    const int w = tid >> 6, l = tid & 63, c = l & 15, q = l >> 4;
    const int g = tid >> 4, cs = tid & 15;  // staging coords
    const int s = blockIdx.x, bh = blockIdx.y;
    const float* kp = key + (size_t)bh * Dv * Nv;

    s16x8 P[4][2];
#pragma unroll
    for (int mt = 0; mt < 4; ++mt)
#pragma unroll
        for (int kc = 0; kc < 2; ++kc)
            P[mt][kc] = load_pfrag(proj, (4 * w + mt) * 16 + c, kc, q);

    float vmax = -3.4e38f;
    for (int ch = 0; ch < NCH; ++ch) {
        const int n0 = s * NSPL + ch * 64;
        if (ch) __syncthreads();
        // stage: thread loads rows 4g..4g+3, cols 4cs..4cs+3 -> b64 transposed
        float4 kk[4];
#pragma unroll
        for (int di = 0; di < 4; ++di)
            kk[di] = *(const float4*)&kp[(4 * g + di) * Nv + n0 + 4 * cs];
#pragma unroll
        for (int j = 0; j < 4; ++j) {
            *(short4*)&KT[4 * cs + j][4 * g] = make_short4(
                (short)f2b(((const float*)&kk[0])[j]),
                (short)f2b(((const float*)&kk[1])[j]),
                (short)f2b(((const float*)&kk[2])[j]),
                (short)f2b(((const float*)&kk[3])[j]));
        }
        __syncthreads();
#pragma unroll
        for (int nt = 0; nt < 4; ++nt) {
            const s16x8 a0 = *(const s16x8*)&KT[nt * 16 + c][q * 8];
            const s16x8 a1 = *(const s16x8*)&KT[nt * 16 + c][32 + q * 8];
#pragma unroll
            for (int mt = 0; mt < 4; ++mt) {
                f32x4 u = {0.f, 0.f, 0.f, 0.f};
                u = __builtin_amdgcn_mfma_f32_16x16x32_bf16(a0, P[mt][0], u, 0, 0, 0);
                u = __builtin_amdgcn_mfma_f32_16x16x32_bf16(a1, P[mt][1], u, 0, 0, 0);
                vmax = fmaxf(vmax, fmaxf(fmaxf(u[0], u[1]), fmaxf(u[2], u[3])));
            }
        }
    }
#pragma unroll
    for (int off = 1; off < 64; off <<= 1)
        vmax = fmaxf(vmax, __shfl_xor(vmax, off, 64));
    if (l == 0) red[w] = vmax;
    __syncthreads();
    if (tid == 0)
        ws[OFF_MAXP + bh * SPL + s] =
            fmaxf(fmaxf(red[0], red[1]), fmaxf(red[2], red[3]));
}

__global__ void favor_stab(float* __restrict__ ws) {
    const int t = threadIdx.x;
    if (t < BHv) {
        float r = -3.4e38f;
        for (int s = 0; s < SPL; ++s) r = fmaxf(r, ws[OFF_MAXP + t * SPL + s]);
        ws[OFF_STAB + t] = r * DNRM;
    }
}

// ---------------------------------------------------------------------------
// kv: U^T = K^T·P^T → exp → phi (wave-private LDS, kc-split) → kv += phi·V^T.
__global__ __launch_bounds__(256, 2) void favor_kv(const float* __restrict__ key,
                                                   const float* __restrict__ value,
                                                   const float* __restrict__ proj,
                                                   float* __restrict__ ws) {
    __shared__ __align__(16) unsigned short KT[64][72];   // [n][d]
    __shared__ __align__(16) unsigned short VL[64][72];   // [d][n]
    __shared__ __align__(16) unsigned short PH[256][40];  // [m][32n half] phi
    const int tid = threadIdx.x;
    const int w = tid >> 6, l = tid & 63, c = l & 15, q = l >> 4;
    const int g = tid >> 4, cs = tid & 15;
    const int s = blockIdx.x, bh = blockIdx.y;
    const float* kp = key + (size_t)bh * Dv * Nv;
    const float* vp = value + (size_t)bh * Dv * Nv;
    const float stab = ws[OFF_STAB + bh];
    const float* dgp = ws + OFF_DIAGK + bh * Nv;

    s16x8 P[4][2];
#pragma unroll
    for (int mt = 0; mt < 4; ++mt)
#pragma unroll
        for (int kc = 0; kc < 2; ++kc)
            P[mt][kc] = load_pfrag(proj, (4 * w + mt) * 16 + c, kc, q);

    f32x4 kva[4][4];
#pragma unroll
    for (int mt = 0; mt < 4; ++mt)
#pragma unroll
        for (int dt = 0; dt < 4; ++dt) kva[mt][dt] = (f32x4){0.f, 0.f, 0.f, 0.f};
    float kn[4] = {0.f, 0.f, 0.f, 0.f};

    for (int ch = 0; ch < NCH; ++ch) {
        const int n0 = s * NSPL + ch * 64;
        if (ch) __syncthreads();
        {
            float4 kk[4], vv[4];
#pragma unroll
            for (int di = 0; di < 4; ++di) {
                kk[di] = *(const float4*)&kp[(4 * g + di) * Nv + n0 + 4 * cs];
                vv[di] = *(const float4*)&vp[(4 * g + di) * Nv + n0 + 4 * cs];
            }
#pragma unroll
            for (int j = 0; j < 4; ++j)
                *(short4*)&KT[4 * cs + j][4 * g] = make_short4(
                    (short)f2b(((const float*)&kk[0])[j]),
                    (short)f2b(((const float*)&kk[1])[j]),
                    (short)f2b(((const float*)&kk[2])[j]),
                    (short)f2b(((const float*)&kk[3])[j]));
#pragma unroll
            for (int di = 0; di < 4; ++di)
                *(short4*)&VL[4 * g + di][4 * cs] = make_short4(
                    (short)f2b(vv[di].x), (short)f2b(vv[di].y),
                    (short)f2b(vv[di].z), (short)f2b(vv[di].w));
        }
        __syncthreads();
#pragma unroll
        for (int h = 0; h < 2; ++h) {
            // GEMM1 on this 32-column half: D[n][m], wave-private m rows
#pragma unroll
            for (int nt2 = 0; nt2 < 2; ++nt2) {
                const int nt = 2 * h + nt2;
                const s16x8 a0 = *(const s16x8*)&KT[nt * 16 + c][q * 8];
                const s16x8 a1 = *(const s16x8*)&KT[nt * 16 + c][32 + q * 8];
                const float4 dg = *(const float4*)&dgp[n0 + nt * 16 + q * 4];
#pragma unroll
                for (int mt = 0; mt < 4; ++mt) {
                    f32x4 u = {0.f, 0.f, 0.f, 0.f};
                    u = __builtin_amdgcn_mfma_f32_16x16x32_bf16(a0, P[mt][0], u, 0, 0, 0);
                    u = __builtin_amdgcn_mfma_f32_16x16x32_bf16(a1, P[mt][1], u, 0, 0, 0);
                    const float e0 = __expf(u[0] * DNRM - dg.x - stab) + EPSV;
                    const float e1 = __expf(u[1] * DNRM - dg.y - stab) + EPSV;
                    const float e2 = __expf(u[2] * DNRM - dg.z - stab) + EPSV;
                    const float e3 = __expf(u[3] * DNRM - dg.w - stab) + EPSV;
                    kn[mt] += (e0 + e1) + (e2 + e3);
                    *(short4*)&PH[(4 * w + mt) * 16 + c][nt2 * 16 + q * 4] =
                        make_short4((short)f2b(e0), (short)f2b(e1),
                                    (short)f2b(e2), (short)f2b(e3));
                }
            }
            // GEMM2 half: kv[m][d] += phi[m][n]·V^T[n][d] (wave-private PH)
            s16x8 bf[4];
#pragma unroll
            for (int dt = 0; dt < 4; ++dt)
                bf[dt] = *(const s16x8*)&VL[dt * 16 + c][h * 32 + q * 8];
#pragma unroll
            for (int mt = 0; mt < 4; ++mt) {
                const s16x8 a = *(const s16x8*)&PH[(4 * w + mt) * 16 + c][q * 8];
#pragma unroll
                for (int dt = 0; dt < 4; ++dt)
                    kva[mt][dt] = __builtin_amdgcn_mfma_f32_16x16x32_bf16(
                        a, bf[dt], kva[mt][dt], 0, 0, 0);
            }
        }
    }
    float* kvp = ws + OFF_KVP + (size_t)(bh * SPL + s) * Mv * Dv;
#pragma unroll
    for (int mt = 0; mt < 4; ++mt) {
        const int mrow = (4 * w + mt) * 16 + 4 * q;
#pragma unroll
        for (int dt = 0; dt < 4; ++dt) {
            const int dcol = dt * 16 + c;
#pragma unroll
            for (int r = 0; r < 4; ++r)
                kvp[(size_t)(mrow + r) * Dv + dcol] = kva[mt][dt][r];
        }
    }
#pragma unroll
    for (int mt = 0; mt < 4; ++mt) {
        kn[mt] += __shfl_xor(kn[mt], 16, 64);
        kn[mt] += __shfl_xor(kn[mt], 32, 64);
    }
    if (q == 0) {
        float* knp = ws + OFF_KNP + (bh * SPL + s) * Mv;
#pragma unroll
        for (int mt = 0; mt < 4; ++mt) knp[(4 * w + mt) * 16 + c] = kn[mt];
    }
}

// ---------------------------------------------------------------------------
// reduce split partials — fully coalesced: thread owns 4 consecutive floats
// of the flattened [m][d] plane; accumulates over the 16 splits.
__global__ __launch_bounds__(256) void favor_kvred(float* __restrict__ ws) {
    const int t = threadIdx.x, f = blockIdx.x, bh = blockIdx.y;
    const int flat = f * 1024 + t * 4;
    const int m = flat >> 6, d0 = flat & 63;
    float4 acc = make_float4(0.f, 0.f, 0.f, 0.f);
    for (int s = 0; s < SPL; ++s) {
        const float4 v =
            *(const float4*)&ws[OFF_KVP + ((size_t)(bh * SPL + s) << 14) + flat];
        acc.x += v.x; acc.y += v.y; acc.z += v.z; acc.w += v.w;
    }
    unsigned short* kvT = (unsigned short*)(ws + OFF_KVT);
    kvT[(bh * 64 + d0 + 0) * 256 + m] = f2b(acc.x);
    kvT[(bh * 64 + d0 + 1) * 256 + m] = f2b(acc.y);
    kvT[(bh * 64 + d0 + 2) * 256 + m] = f2b(acc.z);
    kvT[(bh * 64 + d0 + 3) * 256 + m] = f2b(acc.w);
    if (t < 16) {
        const int mm = f * 16 + t;
        float kk = 0.f;
        for (int s = 0; s < SPL; ++s)
            kk += ws[OFF_KNP + (bh * SPL + s) * Mv + mm];
        ws[OFF_KNF + bh * Mv + mm] = kk;
    }
}

// ---------------------------------------------------------------------------
// out: stage Q (+diag_q) → U = P·Q → col-max → exp → {PHT write + in-register
// norm} → PV MFMA → normalize → coalesced [D][N] store.
__global__ __launch_bounds__(256, 2) void favor_out(const float* __restrict__ query,
                                                    const float* __restrict__ proj,
                                                    const float* __restrict__ ws,
                                                    float* __restrict__ out) {
    __shared__ __align__(16) unsigned short QT[64][72];    // [n][d]
    __shared__ __align__(16) unsigned short PHT[64][264];  // [n][m] phi^T
    __shared__ float dred[16][64];  // diag_q partials [g][n]
    __shared__ float npart[4][64];  // per-wave denominator partials
    __shared__ float knl[256];
    __shared__ float cw[4][64];
    __shared__ float stabl[64];
    __shared__ float dql[64];
    const int tid = threadIdx.x;
    const int w = tid >> 6, l = tid & 63, c = l & 15, q = l >> 4;
    const int g = tid >> 4, cs = tid & 15;
    const int nb = blockIdx.x, bh = blockIdx.y;
    const int n0 = nb * 64;
    const float* qp = query + (size_t)bh * Dv * Nv;
    const unsigned short* kvT =
        (const unsigned short*)(ws + OFF_KVT) + (size_t)bh * 64 * 256;

    // stage Q transposed (b64 writes) + diag_q partials
    {
        float4 qq[4];
#pragma unroll
        for (int di = 0; di < 4; ++di)
            qq[di] = *(const float4*)&qp[(4 * g + di) * Nv + n0 + 4 * cs];
#pragma unroll
        for (int j = 0; j < 4; ++j) {
            const float v0 = ((const float*)&qq[0])[j];
            const float v1 = ((const float*)&qq[1])[j];
            const float v2 = ((const float*)&qq[2])[j];
            const float v3 = ((const float*)&qq[3])[j];
            *(short4*)&QT[4 * cs + j][4 * g] =
                make_short4((short)f2b(v0), (short)f2b(v1), (short)f2b(v2),
                            (short)f2b(v3));
            dred[g][4 * cs + j] = (v0 * v0 + v1 * v1) + (v2 * v2 + v3 * v3);
        }
    }
    knl[tid] = ws[OFF_KNF + bh * Mv + tid];

    s16x8 P[4][2];
#pragma unroll
    for (int mt = 0; mt < 4; ++mt)
#pragma unroll
        for (int kc = 0; kc < 2; ++kc)
            P[mt][kc] = load_pfrag(proj, (4 * w + mt) * 16 + c, kc, q);
    __syncthreads();

    // GEMM_uq: D[m][n], wave w owns m = 64w..64w+63
    f32x4 u[4][4];
#pragma unroll
    for (int mt = 0; mt < 4; ++mt)
#pragma unroll
        for (int nt = 0; nt < 4; ++nt) u[mt][nt] = (f32x4){0.f, 0.f, 0.f, 0.f};
#pragma unroll
    for (int nt = 0; nt < 4; ++nt) {
        const s16x8 b0 = *(const s16x8*)&QT[nt * 16 + c][q * 8];
        const s16x8 b1 = *(const s16x8*)&QT[nt * 16 + c][32 + q * 8];
#pragma unroll
        for (int mt = 0; mt < 4; ++mt) {
            u[mt][nt] =
                __builtin_amdgcn_mfma_f32_16x16x32_bf16(P[mt][0], b0, u[mt][nt], 0, 0, 0);
            u[mt][nt] =
                __builtin_amdgcn_mfma_f32_16x16x32_bf16(P[mt][1], b1, u[mt][nt], 0, 0, 0);
        }
    }
    // per-column max over this wave's 64 m
#pragma unroll
    for (int nt = 0; nt < 4; ++nt) {
        float vm = -3.4e38f;
#pragma unroll
        for (int mt = 0; mt < 4; ++mt)
            vm = fmaxf(vm, fmaxf(fmaxf(u[mt][nt][0], u[mt][nt][1]),
                                 fmaxf(u[mt][nt][2], u[mt][nt][3])));
        vm = fmaxf(vm, __shfl_xor(vm, 16, 64));
        vm = fmaxf(vm, __shfl_xor(vm, 32, 64));
        if (q == 0) cw[w][nt * 16 + c] = vm;
    }
    __syncthreads();
    if (tid < 64) {
        stabl[tid] =
            fmaxf(fmaxf(cw[0][tid], cw[1][tid]), fmaxf(cw[2][tid], cw[3][tid]));
        float dsum = 0.f;
#pragma unroll
        for (int gg = 0; gg < 16; ++gg) dsum += dred[gg][tid];
        dql[tid] = dsum * 0.0625f;
    }
    __syncthreads();
    // exp → PHT (b64 writes) + in-register denominator partials
#pragma unroll
    for (int nt = 0; nt < 4; ++nt) {
        const float sr = stabl[nt * 16 + c];
        const float dq = dql[nt * 16 + c];
        float np = 0.f;
#pragma unroll
        for (int mt = 0; mt < 4; ++mt) {
            const float e0 = __expf((u[mt][nt][0] - sr) * DNRM - dq) + EPSV;
            const float e1 = __expf((u[mt][nt][1] - sr) * DNRM - dq) + EPSV;
            const float e2 = __expf((u[mt][nt][2] - sr) * DNRM - dq) + EPSV;
            const float e3 = __expf((u[mt][nt][3] - sr) * DNRM - dq) + EPSV;
            const int mb = (4 * w + mt) * 16 + 4 * q;
            np += e0 * knl[mb] + e1 * knl[mb + 1] + e2 * knl[mb + 2] +
                  e3 * knl[mb + 3];
            *(short4*)&PHT[nt * 16 + c][mb] = make_short4(
                (short)f2b(e0), (short)f2b(e1), (short)f2b(e2), (short)f2b(e3));
        }
        np += __shfl_xor(np, 16, 64);
        np += __shfl_xor(np, 32, 64);
        if (q == 0) npart[w][nt * 16 + c] = np;
    }
    __syncthreads();
    // PV GEMM: wave w owns n-tile w; kvT B-frags from global (L2-hot)
    f32x4 acc[4];
#pragma unroll
    for (int dt = 0; dt < 4; ++dt) acc[dt] = (f32x4){0.f, 0.f, 0.f, 0.f};
#pragma unroll
    for (int kc = 0; kc < 8; ++kc) {
        const s16x8 a = *(const s16x8*)&PHT[w * 16 + c][kc * 32 + q * 8];
#pragma unroll
        for (int dt = 0; dt < 4; ++dt) {
            const s16x8 b =
                *(const s16x8*)&kvT[(size_t)(dt * 16 + c) * 256 + kc * 32 + q * 8];
            acc[dt] = __builtin_amdgcn_mfma_f32_16x16x32_bf16(a, b, acc[dt], 0, 0, 0);
        }
    }
    __syncthreads();  // PHT reads done; reuse as fp32 out tile [64][68]
    float* ot = (float*)&PHT[0][0];
    float rn[4];
#pragma unroll
    for (int r = 0; r < 4; ++r) {
        const int nl = w * 16 + 4 * q + r;
        rn[r] = 1.0f / ((npart[0][nl] + npart[1][nl]) +
                        (npart[2][nl] + npart[3][nl]));
    }
#pragma unroll
    for (int dt = 0; dt < 4; ++dt)
#pragma unroll
        for (int r = 0; r < 4; ++r)
            ot[(dt * 16 + c) * 68 + (w * 16 + 4 * q + r)] = acc[dt][r] * rn[r];
    __syncthreads();
    float* op = out + (size_t)bh * Dv * Nv;
    {
        const int d = tid >> 2, ng = (tid & 3) * 16;
#pragma unroll
        for (int i = 0; i < 4; ++i) {
            const float4 v = *(const float4*)&ot[d * 68 + ng + i * 4];
            *(float4*)&op[d * Nv + n0 + ng + i * 4] = v;
        }
    }
}

// ---------------------------------------------------------------------------
extern "C" void kernel_launch(void* const* d_in, const int* in_sizes, int n_in,
                              void* d_out, int out_size, void* d_ws, size_t ws_size,
                              hipStream_t stream) {
    const float* q = (const float*)d_in[0];
    const float* k = (const float*)d_in[1];
    const float* v = (const float*)d_in[2];
    const float* proj = (const float*)d_in[3];
    float* ws = (float*)d_ws;
    float* out = (float*)d_out;

    favor_diag<<<dim3(8, 32), 256, 0, stream>>>(k, ws);
    favor_kmax<<<dim3(SPL, 32), 256, 0, stream>>>(k, proj, ws);
    favor_stab<<<1, 64, 0, stream>>>(ws);
    favor_kv<<<dim3(SPL, 32), 256, 0, stream>>>(k, v, proj, ws);
    favor_kvred<<<dim3(16, 32), 256, 0, stream>>>(ws);
    favor_out<<<dim3(Nv / 64, 32), 256, 0, stream>>>(q, proj, ws, out);
}